// Round 12
// baseline (443.602 us; speedup 1.0000x reference)
//
#include <hip/hip_runtime.h>
#include <hip/hip_bf16.h>
#include <hip/hip_fp16.h>

#define BB 16
#define LL 2048
#define DD 128
#define SCALE 0.08838834764831845f
#define CEXP 12.0f
#define NT 32        // k-tiles of 64

typedef _Float16 f16x8 __attribute__((ext_vector_type(8)));
typedef float f32x16 __attribute__((ext_vector_type(16)));

#define MFMA32(a,b,c) __builtin_amdgcn_mfma_f32_32x32x16_f16((a),(b),(c),0,0,0)

// LDS map (pass2): KB 4x16K | VB 4x16K | PB 16K
#define OFF_KB   0
#define OFF_VB   65536
#define OFF_PB   131072
#define LDS_MAIN 147456

#define WAITVM(N)  asm volatile("s_waitcnt vmcnt(" #N ")" ::: "memory")
#define WAITLGKM0  asm volatile("s_waitcnt lgkmcnt(0)" ::: "memory")
#define MEMFENCE   asm volatile("" ::: "memory")
#define SB0        __builtin_amdgcn_sched_barrier(0)

__device__ __forceinline__ f16x8 as_f16x8(uint4 v){
  union { uint4 u; f16x8 h; } x; x.u = v; return x.h;
}
__device__ __forceinline__ unsigned pkf16(float a, float b){
  __half ha = __float2half_rn(a), hb = __float2half_rn(b);
  return (unsigned)__half_as_ushort(ha) | ((unsigned)__half_as_ushort(hb) << 16);
}
__device__ __forceinline__ unsigned pkrtz(float a, float b){
  union { decltype(__builtin_amdgcn_cvt_pkrtz(0.f, 0.f)) h; unsigned u; } x;
  x.h = __builtin_amdgcn_cvt_pkrtz(a, b);
  return x.u;
}
__device__ __forceinline__ void stage16(const unsigned char* g, char* l){
  __builtin_amdgcn_global_load_lds(
      (const __attribute__((address_space(1))) void*)g,
      (__attribute__((address_space(3))) void*)l, 16, 0, 0);
}
__device__ __forceinline__ void stage2(const unsigned char* g, char* l, int soff){
  stage16(g + soff, l + soff);
  stage16(g + soff + 1024, l + soff + 1024);
}

// ---------- prep_kv: K -> fp16 swizzled k-major image | V -> fp16 swizzled d-major ----------
// K image tile (b,t): byte = klocal*256 + ((gd*16)^((klocal&15)<<4)), gd = d/8
// V image tile (b,t): byte = d*128 + ((gk*16)^((d&7)<<4)), gk covers k 8*gk..+7
__global__ __launch_bounds__(256) void prep_kv(
    const float* __restrict__ K, const float* __restrict__ V,
    unsigned char* __restrict__ kimg, unsigned char* __restrict__ vimg)
{
  __shared__ float t[32][65];
  const int bid = blockIdx.x, tid = threadIdx.x;
  if (bid < 2048) {
    const int G = bid*256 + tid;
    const int b = G >> 15;
    const int k = (G >> 4) & 2047;
    const int gd = G & 15;
    const float* src = K + ((size_t)b*LL + k)*DD + gd*8;
    float4 f0 = *(const float4*)(src);
    float4 f1 = *(const float4*)(src + 4);
    uint4 o;
    o.x = pkf16(f0.x, f0.y); o.y = pkf16(f0.z, f0.w);
    o.z = pkf16(f1.x, f1.y); o.w = pkf16(f1.z, f1.w);
    const size_t base = ((size_t)b*NT + (k>>6))*16384;
    *(uint4*)(kimg + base + (k&63)*256 + ((gd*16) ^ ((k&15)<<4))) = o;
  } else {
    const int t2 = bid - 2048;
    const int b = t2 >> 7;
    const int rem = t2 & 127;
    const int kt = rem >> 2, dt = rem & 3;
    const int k0 = kt*64, d0 = dt*32;
    const int kl = tid >> 2, dq = (tid & 3)*8;
    const float* src = V + ((size_t)b*LL + k0 + kl)*DD + d0 + dq;
    float4 f0 = *(const float4*)(src);
    float4 f1 = *(const float4*)(src + 4);
    t[dq+0][kl] = f0.x; t[dq+1][kl] = f0.y; t[dq+2][kl] = f0.z; t[dq+3][kl] = f0.w;
    t[dq+4][kl] = f1.x; t[dq+5][kl] = f1.y; t[dq+6][kl] = f1.z; t[dq+7][kl] = f1.w;
    __syncthreads();
    const int dl = tid >> 3, kg = tid & 7;
    const int d = d0 + dl;
    uint4 o;
    o.x = pkf16(t[dl][kg*8+0], t[dl][kg*8+1]);
    o.y = pkf16(t[dl][kg*8+2], t[dl][kg*8+3]);
    o.z = pkf16(t[dl][kg*8+4], t[dl][kg*8+5]);
    o.w = pkf16(t[dl][kg*8+6], t[dl][kg*8+7]);
    const size_t base = ((size_t)b*NT + kt)*16384;
    *(uint4*)(vimg + base + d*128 + ((kg*16) ^ ((d&7)<<4))) = o;
  }
}

// ---------- pass1: barrier-free streaming mask-pack + QK + expsum ----------
// WG = 512 thr = 8 waves (p = q-half, ww = k-quarter). No inter-wave coupling in hot loop.
__global__ __launch_bounds__(512, 4) void pass1(
    const float* __restrict__ Q, const int* __restrict__ M,
    const unsigned char* __restrict__ KIMG,
    unsigned int* __restrict__ BM, float* __restrict__ Sums)
{
  __shared__ float RED[2][4][32];
  const int tid = threadIdx.x;
  const int w = tid >> 6, l = tid & 63;
  const int c = l & 31, hi = l >> 5;
  const int p = w >> 2, ww = w & 3;

  const int bid = blockIdx.x;
  const int xcd = bid & 7, jj = bid >> 3;          // 512 WGs
  const int b = xcd*2 + (jj >> 5);
  const int q0 = (jj & 31) * 64;
  const int qrow = q0 + p*32 + c;

  // Q fragments (fp16)
  uint4 qf[8];
  const float* qp0 = Q + ((size_t)b*LL + qrow)*DD;
#pragma unroll
  for (int s = 0; s < 8; ++s) {
    const float4 f0 = *(const float4*)(qp0 + s*16 + hi*8);
    const float4 f1 = *(const float4*)(qp0 + s*16 + hi*8 + 4);
    uint4 qv;
    qv.x = pkf16(f0.x, f0.y); qv.y = pkf16(f0.z, f0.w);
    qv.z = pkf16(f1.x, f1.y); qv.w = pkf16(f1.z, f1.w);
    qf[s] = qv;
  }

  const size_t imgb = ((size_t)b * NT) * 16384;
  const int kswz = (c & 15) << 4;
  const int* Mrow = M + ((size_t)b*LL + qrow)*LL;
  const size_t bmrow = ((size_t)b*LL + qrow)*64;

  float psum[4] = {0.f, 0.f, 0.f, 0.f};
#pragma unroll 4
  for (int t = 0; t < 16; ++t) {
    const int kbase = ww*512 + t*32;
    const int tile  = kbase >> 6;
    const int sub2  = (kbase >> 5) & 1;
    const unsigned char* kbg = KIMG + imgb + (size_t)tile*16384 + (sub2*32 + c)*256;
    uint4 kf[8];
#pragma unroll
    for (int s = 0; s < 8; ++s)
      kf[s] = *(const uint4*)(kbg + (((s*2+hi)*16) ^ kswz));
    const int4 m0 = *(const int4*)(Mrow + kbase + hi*4);
    const int4 m1 = *(const int4*)(Mrow + kbase + hi*4 + 8);
    const int4 m2 = *(const int4*)(Mrow + kbase + hi*4 + 16);
    const int4 m3 = *(const int4*)(Mrow + kbase + hi*4 + 24);
    f32x16 acc;
#pragma unroll
    for (int i = 0; i < 16; ++i) acc[i] = 0.f;
#pragma unroll
    for (int s = 0; s < 8; ++s) acc = MFMA32(as_f16x8(kf[s]), as_f16x8(qf[s]), acc);
    const unsigned w16 = (m0.x?0x1u:0u)|(m0.y?0x2u:0u)|(m0.z?0x4u:0u)|(m0.w?0x8u:0u)
                       | (m1.x?0x100u:0u)|(m1.y?0x200u:0u)|(m1.z?0x400u:0u)|(m1.w?0x800u:0u)
                       | (m2.x?0x10000u:0u)|(m2.y?0x20000u:0u)|(m2.z?0x40000u:0u)|(m2.w?0x80000u:0u)
                       | (m3.x?0x1000000u:0u)|(m3.y?0x2000000u:0u)|(m3.z?0x4000000u:0u)|(m3.w?0x8000000u:0u);
    const unsigned pw = __shfl_xor(w16, 32);
    if (l < 32) BM[bmrow + ww*16 + t] = w16 | (pw << 4);
#pragma unroll
    for (int i = 0; i < 16; ++i) {
      const float sv = ((w16>>((i&3)+8*(i>>2)))&1u) ? fmaf(acc[i], SCALE, -CEXP) : -1.0e9f;
      psum[i&3] += __expf(sv);
    }
  }
  float s = (psum[0] + psum[1]) + (psum[2] + psum[3]);
  s += __shfl_xor(s, 32);
  if (l < 32) RED[p][ww][c] = s;
  __syncthreads();
  if (tid < 64) {
    const int p2 = tid >> 5, c2 = tid & 31;
    const float tot = (RED[p2][0][c2] + RED[p2][1][c2])
                    + (RED[p2][2][c2] + RED[p2][3][c2]);
    Sums[(size_t)b*LL + q0 + p2*32 + c2] = tot;
  }
}

// QK^T into aA/aB from KB[buf]
#define QKCOMPUTE(BUFIDX) \
  const char* kb = KB + (BUFIDX)*16384 + krow*256; \
  f32x16 aA, aB; \
  _Pragma("unroll") for (int i=0;i<16;++i){aA[i]=0.f;aB[i]=0.f;} \
  _Pragma("unroll") for (int s=0;s<4;++s){ \
    uint4 af = *(const uint4*)(kb + (((s*2+hi)*16) ^ kswz)); \
    aA = MFMA32(as_f16x8(af), as_f16x8(qf[s]), aA); } \
  _Pragma("unroll") for (int s=4;s<8;++s){ \
    uint4 af = *(const uint4*)(kb + (((s*2+hi)*16) ^ kswz)); \
    aB = MFMA32(as_f16x8(af), as_f16x8(qf[s]), aB); }

#define P2BODY(RR, NTOK) do { \
  WAITVM(NTOK); \
  __builtin_amdgcn_s_barrier(); \
  MEMFENCE; \
  const unsigned bn2 = BMl[2*(((RR)+2)&31)]; \
  SB0; \
  stage2(KIMG + imgb + (size_t)(((RR)+3)&31)*16384, KB + (((RR)+3)&3)*16384, soff); \
  stage2(VIMG + imgb + (size_t)(((RR)+3)&31)*16384, VB + (((RR)+3)&3)*16384, soff); \
  SB0; \
  QKCOMPUTE((RR)&3); \
  const unsigned bwh = bcur >> (4*hi); \
  float pv[16]; \
  _Pragma("unroll") for (int i=0;i<16;++i){ \
    const float sv = ((bwh>>((i&3)+8*(i>>2)))&1u) ? fmaf(aA[i]+aB[i], SCALE, -CEXP) : -1.0e9f; \
    pv[i] = __expf(sv) * inv; } \
  { float* pr = Prow + (size_t)(RR)*64 + sub*32 + hi*4; \
    float4 o; \
    o.x=pv[0];  o.y=pv[1];  o.z=pv[2];  o.w=pv[3];  *(float4*)(pr)    = o; \
    o.x=pv[4];  o.y=pv[5];  o.z=pv[6];  o.w=pv[7];  *(float4*)(pr+8)  = o; \
    o.x=pv[8];  o.y=pv[9];  o.z=pv[10]; o.w=pv[11]; *(float4*)(pr+16) = o; \
    o.x=pv[12]; o.y=pv[13]; o.z=pv[14]; o.w=pv[15]; *(float4*)(pr+24) = o; } \
  SB0; \
  { char* pb = PB + p*4096 + sub*2048; \
    uint2 u; \
    u.x = pkrtz(pv[0],pv[1]);   u.y = pkrtz(pv[2],pv[3]);   *(uint2*)(pb + c*16 + hi*8) = u; \
    u.x = pkrtz(pv[4],pv[5]);   u.y = pkrtz(pv[6],pv[7]);   *(uint2*)(pb + (c+32)*16 + hi*8) = u; \
    u.x = pkrtz(pv[8],pv[9]);   u.y = pkrtz(pv[10],pv[11]); *(uint2*)(pb + 1024 + c*16 + hi*8) = u; \
    u.x = pkrtz(pv[12],pv[13]); u.y = pkrtz(pv[14],pv[15]); *(uint2*)(pb + 1024 + (c+32)*16 + hi*8) = u; } \
  WAITLGKM0; \
  __builtin_amdgcn_s_barrier(); \
  MEMFENCE; \
  _Pragma("unroll") for (int s2=0;s2<2;++s2){ \
    _Pragma("unroll") for (int k2=0;k2<2;++k2){ \
      const uint4 afr = *(const uint4*)(PB + p*4096 + s2*2048 + k2*1024 + l*16); \
      const int gix = s2*4 + k2*2 + hi; \
      const int d0v = sub*64 + c; \
      const uint4 b0 = *(const uint4*)(VB + ((RR)&3)*16384 + d0v*128 + ((gix*16) ^ ((d0v&7)<<4))); \
      ctx0 = MFMA32(as_f16x8(afr), as_f16x8(b0), ctx0); \
      const int d1v = sub*64 + 32 + c; \
      const uint4 b1 = *(const uint4*)(VB + ((RR)&3)*16384 + d1v*128 + ((gix*16) ^ ((d1v&7)<<4))); \
      ctx1 = MFMA32(as_f16x8(afr), as_f16x8(b1), ctx1); } } \
  bcur = bn1; bn1 = bn2; \
} while(0)

// ---------- pass2: 1 WG/CU = (batch, 128 q-rows), 8 waves ----------
__global__ __launch_bounds__(512) void pass2(
    const float* __restrict__ Q, const unsigned int* __restrict__ BM,
    const float* __restrict__ Sums,
    const unsigned char* __restrict__ KIMG, const unsigned char* __restrict__ VIMG,
    float* __restrict__ ctxout, float* __restrict__ pout)
{
  extern __shared__ char lds[];
  char* KB = lds + OFF_KB;
  char* VB = lds + OFF_VB;
  char* PB = lds + OFF_PB;

  const int tid = threadIdx.x;
  const int w = tid >> 6, l = tid & 63;
  const int c = l & 31, hi = l >> 5;
  const int p = w >> 1, sub = w & 1;

  const int bid = blockIdx.x;
  const int xcd = bid & 7, jj = bid >> 3;
  const int b = xcd*2 + (jj >> 4);
  const int q0 = (jj & 15) * 128;
  const int qrow = q0 + p*32 + c;

  // Q fragments (fp16)
  uint4 qf[8];
  const float* qp0 = Q + ((size_t)b*LL + qrow)*DD;
#pragma unroll
  for (int s = 0; s < 8; ++s) {
    const float4 f0 = *(const float4*)(qp0 + s*16 + hi*8);
    const float4 f1 = *(const float4*)(qp0 + s*16 + hi*8 + 4);
    uint4 qv;
    qv.x = pkf16(f0.x, f0.y); qv.y = pkf16(f0.z, f0.w);
    qv.z = pkf16(f1.x, f1.y); qv.w = pkf16(f1.z, f1.w);
    qf[s] = qv;
  }

  const size_t imgb = ((size_t)b * NT) * 16384;
  const int soff = w*2048 + l*16;
  const unsigned int* BMl = BM + ((size_t)b*LL + qrow)*64 + sub;
  const int krow = sub*32 + c;
  const int kswz = (c & 15) << 4;

  const float tot = Sums[(size_t)b*LL + qrow];
  const float inv = 1.0f / fmaxf(tot, 1e-35f);

  // prologue: stage K,V tiles 0..2
  stage2(KIMG + imgb + 0*16384, KB + 0*16384, soff);
  stage2(VIMG + imgb + 0*16384, VB + 0*16384, soff); SB0;
  unsigned bcur = BMl[0]; SB0;
  stage2(KIMG + imgb + 1*16384, KB + 1*16384, soff);
  stage2(VIMG + imgb + 1*16384, VB + 1*16384, soff); SB0;
  unsigned bn1 = BMl[2]; SB0;
  stage2(KIMG + imgb + 2*16384, KB + 2*16384, soff);
  stage2(VIMG + imgb + 2*16384, VB + 2*16384, soff); SB0;

  f32x16 ctx0, ctx1;
#pragma unroll
  for (int i = 0; i < 16; ++i) { ctx0[i] = 0.f; ctx1[i] = 0.f; }
  float* Prow = pout + ((size_t)b*LL + qrow)*LL;

  P2BODY(0, 10);
  P2BODY(1, 14);
  P2BODY(2, 18);
#pragma unroll 1
  for (int r = 3; r < 32; ++r) {
    P2BODY(r, 22);
  }

  // ---- ctx epilogue
#pragma unroll
  for (int reg = 0; reg < 16; ++reg) {
    const int q = q0 + p*32 + (reg&3) + 8*(reg>>2) + 4*hi;
    float* cr = ctxout + ((size_t)b*LL + q)*DD;
    cr[sub*64 + c]      = ctx0[reg];
    cr[sub*64 + 32 + c] = ctx1[reg];
  }
}

// ---------- fallback (ws too small): simple correct version ----------
__global__ __launch_bounds__(256) void attn_naive(
    const float* __restrict__ Q, const float* __restrict__ K,
    const float* __restrict__ V, const int* __restrict__ M,
    float* __restrict__ ctx, float* __restrict__ pout)
{
  const int b = blockIdx.x >> 11;
  const int q = blockIdx.x & (LL-1);
  __shared__ float s[LL];
  __shared__ float red[256];
  const int tid = threadIdx.x;
  const float* qp = Q + ((size_t)b*LL + q)*DD;
  for (int kk = tid; kk < LL; kk += 256) {
    const float* kp = K + ((size_t)b*LL + kk)*DD;
    float a = 0.f;
    for (int d = 0; d < DD; ++d) a += qp[d]*kp[d];
    s[kk] = M[((size_t)b*LL + q)*LL + kk] ? a*SCALE : -1e9f;
  }
  __syncthreads();
  float mx = -3e38f;
  for (int kk = tid; kk < LL; kk += 256) mx = fmaxf(mx, s[kk]);
  red[tid] = mx; __syncthreads();
  for (int o = 128; o >= 1; o >>= 1) {
    if (tid < o) red[tid] = fmaxf(red[tid], red[tid+o]);
    __syncthreads();
  }
  const float mrow = red[0]; __syncthreads();
  float sm = 0.f;
  for (int kk = tid; kk < LL; kk += 256) { float e = __expf(s[kk]-mrow); s[kk] = e; sm += e; }
  red[tid] = sm; __syncthreads();
  for (int o = 128; o >= 1; o >>= 1) {
    if (tid < o) red[tid] += red[tid+o];
    __syncthreads();
  }
  const float inv = 1.0f / red[0]; __syncthreads();
  float* prow = pout + ((size_t)b*LL + q)*LL;
  for (int kk = tid; kk < LL; kk += 256) { s[kk] *= inv; prow[kk] = s[kk]; }
  __syncthreads();
  if (tid < DD) {
    float a = 0.f;
    for (int kk = 0; kk < LL; ++kk) a += s[kk]*V[((size_t)b*LL + kk)*DD + tid];
    ctx[((size_t)b*LL + q)*DD + tid] = a;
  }
}

extern "C" void kernel_launch(void* const* d_in, const int* in_sizes, int n_in,
                              void* d_out, int out_size, void* d_ws, size_t ws_size,
                              hipStream_t stream) {
  (void)in_sizes; (void)n_in; (void)out_size;
  const float* Q = (const float*)d_in[0];
  const float* K = (const float*)d_in[1];
  const float* V = (const float*)d_in[2];
  const int*   M = (const int*)d_in[3];
  float* ctx  = (float*)d_out;
  float* pout = ctx + (size_t)BB*LL*DD;
  const size_t IMG = (size_t)BB*NT*16384;        // 8 MB per image
  const size_t NBM = (size_t)BB*LL*(LL/32);      // 2.1M words = 8 MB
  const size_t NSUM = (size_t)BB*LL;             // 32K floats
  const size_t WS_NEED = IMG*2 + NBM*4 + NSUM*4;
  if (ws_size >= WS_NEED) {
    unsigned char* kimg = (unsigned char*)d_ws;
    unsigned char* vimg = kimg + IMG;
    unsigned int*  bmw  = (unsigned int*)(vimg + IMG);
    float*         sums = (float*)(bmw + NBM);
    hipFuncSetAttribute(reinterpret_cast<const void*>(pass2),
                        hipFuncAttributeMaxDynamicSharedMemorySize, LDS_MAIN);
    prep_kv<<<4096, 256, 0, stream>>>(K, V, kimg, vimg);
    pass1<<<512, 512, 0, stream>>>(Q, M, kimg, bmw, sums);
    pass2<<<256, 512, LDS_MAIN, stream>>>(Q, bmw, sums, kimg, vimg, ctx, pout);
  } else {
    attn_naive<<<BB*LL, 256, 0, stream>>>(Q, K, V, M, ctx, pout);
  }
}

// Round 13
// 203.729 us; speedup vs baseline: 2.1774x; 2.1774x over previous
//
#include <hip/hip_runtime.h>
#include <hip/hip_bf16.h>
#include <hip/hip_fp16.h>

#define BB 16
#define LL 2048
#define DD 128
#define SCALE 0.08838834764831845f
#define CEXP 12.0f
#define NT 32        // k-tiles of 64

typedef _Float16 f16x8 __attribute__((ext_vector_type(8)));
typedef float f32x16 __attribute__((ext_vector_type(16)));

#define MFMA32(a,b,c) __builtin_amdgcn_mfma_f32_32x32x16_f16((a),(b),(c),0,0,0)

// LDS map (main): KB 4x16K | VB 4x16K | (16K spare) | RED 1K
#define OFF_KB   0
#define OFF_VB   65536
#define OFF_RED  147456
#define LDS_MAIN 148480

#define WAITVM(N)  asm volatile("s_waitcnt vmcnt(" #N ")" ::: "memory")
#define MEMFENCE   asm volatile("" ::: "memory")
#define SB0        __builtin_amdgcn_sched_barrier(0)

__device__ __forceinline__ f16x8 as_f16x8(uint4 v){
  union { uint4 u; f16x8 h; } x; x.u = v; return x.h;
}
__device__ __forceinline__ unsigned pkf16(float a, float b){
  __half ha = __float2half_rn(a), hb = __float2half_rn(b);
  return (unsigned)__half_as_ushort(ha) | ((unsigned)__half_as_ushort(hb) << 16);
}
__device__ __forceinline__ unsigned pkrtz(float a, float b){
  union { decltype(__builtin_amdgcn_cvt_pkrtz(0.f, 0.f)) h; unsigned u; } x;
  x.h = __builtin_amdgcn_cvt_pkrtz(a, b);
  return x.u;
}
// permlane32_swap: a.high-lanes <-> b.low-lanes; returns {new_a, new_b}
__device__ __forceinline__ void pl32swap(unsigned a, unsigned b,
                                         unsigned* ra, unsigned* rb){
  union { decltype(__builtin_amdgcn_permlane32_swap(0u, 0u, false, false)) v;
          uint2 u; } x;
  x.v = __builtin_amdgcn_permlane32_swap(a, b, false, false);
  *ra = x.u.x; *rb = x.u.y;
}
__device__ __forceinline__ void stage16(const unsigned char* g, char* l){
  __builtin_amdgcn_global_load_lds(
      (const __attribute__((address_space(1))) void*)g,
      (__attribute__((address_space(3))) void*)l, 16, 0, 0);
}
__device__ __forceinline__ void stage2(const unsigned char* g, char* l, int soff){
  stage16(g + soff, l + soff);
  stage16(g + soff + 1024, l + soff + 1024);
}

// ---------- prep: mask->bits | K -> fp16 swizzled k-major image | V -> fp16 swizzled d-major ----------
__global__ __launch_bounds__(256) void prep_all(
    const float* __restrict__ K, const float* __restrict__ V,
    const int* __restrict__ M,
    unsigned char* __restrict__ kimg, unsigned char* __restrict__ vimg,
    unsigned int* __restrict__ bm)
{
  __shared__ float t[32][65];
  const int bid = blockIdx.x, tid = threadIdx.x;
  if (bid < 8192) {
    const size_t wi = (size_t)bid * 256 + tid;      // word index, 2^21 total
    const int* mp = M + wi * 32;
    unsigned int wrd = 0;
#pragma unroll
    for (int j = 0; j < 8; ++j) {
      int4 v = *(const int4*)(mp + j*4);
      wrd |= (v.x ? 1u : 0u) << (4*j)
          |  (v.y ? 1u : 0u) << (4*j+1)
          |  (v.z ? 1u : 0u) << (4*j+2)
          |  (v.w ? 1u : 0u) << (4*j+3);
    }
    bm[wi] = wrd;
  } else if (bid < 10240) {
    const int G = (bid - 8192)*256 + tid;
    const int b = G >> 15;
    const int k = (G >> 4) & 2047;
    const int gd = G & 15;
    const float* src = K + ((size_t)b*LL + k)*DD + gd*8;
    float4 f0 = *(const float4*)(src);
    float4 f1 = *(const float4*)(src + 4);
    uint4 o;
    o.x = pkf16(f0.x, f0.y); o.y = pkf16(f0.z, f0.w);
    o.z = pkf16(f1.x, f1.y); o.w = pkf16(f1.z, f1.w);
    const size_t base = ((size_t)b*NT + (k>>6))*16384;
    *(uint4*)(kimg + base + (k&63)*256 + ((gd*16) ^ ((k&15)<<4))) = o;
  } else {
    const int t2 = bid - 10240;
    const int b = t2 >> 7;
    const int rem = t2 & 127;
    const int kt = rem >> 2, dt = rem & 3;
    const int k0 = kt*64, d0 = dt*32;
    const int kl = tid >> 2, dq = (tid & 3)*8;
    const float* src = V + ((size_t)b*LL + k0 + kl)*DD + d0 + dq;
    float4 f0 = *(const float4*)(src);
    float4 f1 = *(const float4*)(src + 4);
    t[dq+0][kl] = f0.x; t[dq+1][kl] = f0.y; t[dq+2][kl] = f0.z; t[dq+3][kl] = f0.w;
    t[dq+4][kl] = f1.x; t[dq+5][kl] = f1.y; t[dq+6][kl] = f1.z; t[dq+7][kl] = f1.w;
    __syncthreads();
    const int dl = tid >> 3, kg = tid & 7;
    const int d = d0 + dl;
    uint4 o;
    o.x = pkf16(t[dl][kg*8+0], t[dl][kg*8+1]);
    o.y = pkf16(t[dl][kg*8+2], t[dl][kg*8+3]);
    o.z = pkf16(t[dl][kg*8+4], t[dl][kg*8+5]);
    o.w = pkf16(t[dl][kg*8+6], t[dl][kg*8+7]);
    const size_t base = ((size_t)b*NT + kt)*16384;
    *(uint4*)(vimg + base + d*128 + ((kg*16) ^ ((d&7)<<4))) = o;
  }
}

// QK^T into aA/aB from KB[buf]
#define QKCOMPUTE(BUFIDX) \
  const char* kb = KB + (BUFIDX)*16384 + krow*256; \
  f32x16 aA, aB; \
  _Pragma("unroll") for (int i=0;i<16;++i){aA[i]=0.f;aB[i]=0.f;} \
  _Pragma("unroll") for (int s=0;s<4;++s){ \
    uint4 af = *(const uint4*)(kb + (((s*2+hi)*16) ^ kswz)); \
    aA = MFMA32(as_f16x8(af), as_f16x8(qf[s]), aA); } \
  _Pragma("unroll") for (int s=4;s<8;++s){ \
    uint4 af = *(const uint4*)(kb + (((s*2+hi)*16) ^ kswz)); \
    aB = MFMA32(as_f16x8(af), as_f16x8(qf[s]), aB); }

#define P1BODY(RR) do { \
  WAITVM(6); \
  __builtin_amdgcn_s_barrier(); \
  MEMFENCE; \
  const unsigned bn2 = BMl[2*(((RR)+2)&31)]; \
  SB0; \
  stage2(KIMG + imgb + (size_t)(((RR)+3)&31)*16384, KB + (((RR)+3)&3)*16384, soff); \
  SB0; \
  QKCOMPUTE((RR)&3); \
  const unsigned bwh = bcur >> (4*hi); \
  _Pragma("unroll") for (int i=0;i<16;++i){ \
    const float sv = ((bwh>>((i&3)+8*(i>>2)))&1u) ? fmaf(aA[i]+aB[i], SCALE, -CEXP) : -1.0e9f; \
    psum[i&3] += __expf(sv); } \
  bcur = bn1; bn1 = bn2; \
} while(0)

// pass 2 round: QK -> exp -> P f32 store -> in-register A-frags (cvt_pk + permlane32_swap)
// -> per-wave PV partial accumulate. ONE barrier per round, no LDS P round-trip.
#define P2BODY(RR, NTOK) do { \
  WAITVM(NTOK); \
  __builtin_amdgcn_s_barrier(); \
  MEMFENCE; \
  const unsigned bn2 = BMl[2*(((RR)+2)&31)]; \
  SB0; \
  stage2(KIMG + imgb + (size_t)(((RR)+3)&31)*16384, KB + (((RR)+3)&3)*16384, soff); \
  stage2(VIMG + imgb + (size_t)(((RR)+3)&31)*16384, VB + (((RR)+3)&3)*16384, soff); \
  SB0; \
  QKCOMPUTE((RR)&3); \
  const unsigned bwh = bcur >> (4*hi); \
  float pv[16]; \
  _Pragma("unroll") for (int i=0;i<16;++i){ \
    const float sv = ((bwh>>((i&3)+8*(i>>2)))&1u) ? fmaf(aA[i]+aB[i], SCALE, -CEXP) : -1.0e9f; \
    pv[i] = __expf(sv) * inv; } \
  { float* pr = Prow + (size_t)(RR)*64 + sub*32 + hi*4; \
    float4 o; \
    o.x=pv[0];  o.y=pv[1];  o.z=pv[2];  o.w=pv[3];  *(float4*)(pr)    = o; \
    o.x=pv[4];  o.y=pv[5];  o.z=pv[6];  o.w=pv[7];  *(float4*)(pr+8)  = o; \
    o.x=pv[8];  o.y=pv[9];  o.z=pv[10]; o.w=pv[11]; *(float4*)(pr+16) = o; \
    o.x=pv[12]; o.y=pv[13]; o.z=pv[14]; o.w=pv[15]; *(float4*)(pr+24) = o; } \
  SB0; \
  uint4 af0, af1; \
  { unsigned r0a, r0b, r1a, r1b; \
    pl32swap(pkrtz(pv[0],pv[1]), pkrtz(pv[4],pv[5]), &r0a, &r0b); \
    pl32swap(pkrtz(pv[2],pv[3]), pkrtz(pv[6],pv[7]), &r1a, &r1b); \
    af0.x = r0a; af0.y = r1a; af0.z = r0b; af0.w = r1b; \
    pl32swap(pkrtz(pv[8],pv[9]),  pkrtz(pv[12],pv[13]), &r0a, &r0b); \
    pl32swap(pkrtz(pv[10],pv[11]), pkrtz(pv[14],pv[15]), &r1a, &r1b); \
    af1.x = r0a; af1.y = r1a; af1.z = r0b; af1.w = r1b; } \
  { const char* vbb = VB + ((RR)&3)*16384; \
    const int d0v = 0*32 + c, d1v = 1*32 + c, d2v = 2*32 + c, d3v = 3*32 + c; \
    const int g0 = sub*4 + hi, g1 = sub*4 + 2 + hi; \
    acc0 = MFMA32(as_f16x8(af0), as_f16x8(*(const uint4*)(vbb + d0v*128 + ((g0*16) ^ ((d0v&7)<<4)))), acc0); \
    acc1 = MFMA32(as_f16x8(af0), as_f16x8(*(const uint4*)(vbb + d1v*128 + ((g0*16) ^ ((d1v&7)<<4)))), acc1); \
    acc2 = MFMA32(as_f16x8(af0), as_f16x8(*(const uint4*)(vbb + d2v*128 + ((g0*16) ^ ((d2v&7)<<4)))), acc2); \
    acc3 = MFMA32(as_f16x8(af0), as_f16x8(*(const uint4*)(vbb + d3v*128 + ((g0*16) ^ ((d3v&7)<<4)))), acc3); \
    acc0 = MFMA32(as_f16x8(af1), as_f16x8(*(const uint4*)(vbb + d0v*128 + ((g1*16) ^ ((d0v&7)<<4)))), acc0); \
    acc1 = MFMA32(as_f16x8(af1), as_f16x8(*(const uint4*)(vbb + d1v*128 + ((g1*16) ^ ((d1v&7)<<4)))), acc1); \
    acc2 = MFMA32(as_f16x8(af1), as_f16x8(*(const uint4*)(vbb + d2v*128 + ((g1*16) ^ ((d2v&7)<<4)))), acc2); \
    acc3 = MFMA32(as_f16x8(af1), as_f16x8(*(const uint4*)(vbb + d3v*128 + ((g1*16) ^ ((d3v&7)<<4)))), acc3); } \
  bcur = bn1; bn1 = bn2; \
} while(0)

// ---------- main: 1 WG/CU = (batch, 128 q-rows), 8 waves, two passes ----------
__global__ __launch_bounds__(512) void attn_main(
    const float* __restrict__ Q, const unsigned int* __restrict__ BM,
    const unsigned char* __restrict__ KIMG, const unsigned char* __restrict__ VIMG,
    float* __restrict__ ctxout, float* __restrict__ pout)
{
  extern __shared__ char lds[];
  char* KB = lds + OFF_KB;
  char* VB = lds + OFF_VB;
  float* RED = (float*)(lds + OFF_RED);

  const int tid = threadIdx.x;
  const int w = tid >> 6, l = tid & 63;
  const int c = l & 31, hi = l >> 5;
  const int p = w >> 1, sub = w & 1;

  const int bid = blockIdx.x;
  const int xcd = bid & 7, jj = bid >> 3;
  const int b = xcd*2 + (jj >> 4);
  const int q0 = (jj & 15) * 128;
  const int qrow = q0 + p*32 + c;

  // Q fragments (fp16)
  uint4 qf[8];
  const float* qp0 = Q + ((size_t)b*LL + qrow)*DD;
#pragma unroll
  for (int s = 0; s < 8; ++s) {
    const float4 f0 = *(const float4*)(qp0 + s*16 + hi*8);
    const float4 f1 = *(const float4*)(qp0 + s*16 + hi*8 + 4);
    uint4 qv;
    qv.x = pkf16(f0.x, f0.y); qv.y = pkf16(f0.z, f0.w);
    qv.z = pkf16(f1.x, f1.y); qv.w = pkf16(f1.z, f1.w);
    qf[s] = qv;
  }

  const size_t imgb = ((size_t)b * NT) * 16384;
  const int soff = w*2048 + l*16;
  const unsigned int* BMl = BM + ((size_t)b*LL + qrow)*64 + sub;
  const int krow = sub*32 + c;
  const int kswz = (c & 15) << 4;

  // ---------------- PASS 1: row sums of exp(S - CEXP) ----------------
  stage2(KIMG + imgb + 0*16384, KB + 0*16384, soff); SB0;
  unsigned bcur = BMl[0]; SB0;
  stage2(KIMG + imgb + 1*16384, KB + 1*16384, soff); SB0;
  unsigned bn1 = BMl[2]; SB0;
  stage2(KIMG + imgb + 2*16384, KB + 2*16384, soff); SB0;

  float psum[4] = {0.f, 0.f, 0.f, 0.f};
#pragma unroll 1
  for (int r = 0; r < 32; ++r) {
    P1BODY(r);
  }
  float sum = (psum[0] + psum[1]) + (psum[2] + psum[3]);
  sum += __shfl_xor(sum, 32);
  __syncthreads();                       // drains tail dummy stages too
  if (l < 32) RED[(p*2+sub)*32 + c] = sum;
  __syncthreads();
  float tot = RED[(p*2+sub)*32 + c] + RED[(p*2+(1-sub))*32 + c];
  tot = fmaxf(tot, 1e-35f);
  const float inv = 1.0f / tot;
  __syncthreads();

  // ---------------- PASS 2: P = exp(S-CEXP)*inv, write P, ctx = P*V (in-register PV) ----------------
  stage2(KIMG + imgb + 0*16384, KB + 0*16384, soff);
  stage2(VIMG + imgb + 0*16384, VB + 0*16384, soff); SB0;
  bcur = BMl[0]; SB0;
  stage2(KIMG + imgb + 1*16384, KB + 1*16384, soff);
  stage2(VIMG + imgb + 1*16384, VB + 1*16384, soff); SB0;
  bn1 = BMl[2]; SB0;
  stage2(KIMG + imgb + 2*16384, KB + 2*16384, soff);
  stage2(VIMG + imgb + 2*16384, VB + 2*16384, soff); SB0;

  f32x16 acc0, acc1, acc2, acc3;
#pragma unroll
  for (int i = 0; i < 16; ++i) { acc0[i] = 0.f; acc1[i] = 0.f; acc2[i] = 0.f; acc3[i] = 0.f; }
  float* Prow = pout + ((size_t)b*LL + qrow)*LL;

  P2BODY(0, 10);
  P2BODY(1, 14);
  P2BODY(2, 18);
#pragma unroll 1
  for (int r = 3; r < 32; ++r) {
    P2BODY(r, 22);
  }

  // ---- epilogue: sum the two sub-wave partial ctx, then store
  WAITVM(0);                             // drain wrap-around dummy stages before reusing KB
  __syncthreads();
  float* xch = (float*)(lds + OFF_KB);   // 32 KB used of 64 KB
  if (sub == 1) {
#pragma unroll
    for (int i = 0; i < 16; ++i) {
      xch[p*4096 + 0*1024 + i*64 + l] = acc0[i];
      xch[p*4096 + 1*1024 + i*64 + l] = acc1[i];
      xch[p*4096 + 2*1024 + i*64 + l] = acc2[i];
      xch[p*4096 + 3*1024 + i*64 + l] = acc3[i];
    }
  }
  __syncthreads();
  if (sub == 0) {
#pragma unroll
    for (int i = 0; i < 16; ++i) {
      const int q = q0 + p*32 + (i&3) + 8*(i>>2) + 4*hi;
      float* cr = ctxout + ((size_t)b*LL + q)*DD;
      cr[0*32 + c] = acc0[i] + xch[p*4096 + 0*1024 + i*64 + l];
      cr[1*32 + c] = acc1[i] + xch[p*4096 + 1*1024 + i*64 + l];
      cr[2*32 + c] = acc2[i] + xch[p*4096 + 2*1024 + i*64 + l];
      cr[3*32 + c] = acc3[i] + xch[p*4096 + 3*1024 + i*64 + l];
    }
  }
}

// ---------- fallback (ws too small): simple correct version ----------
__global__ __launch_bounds__(256) void attn_naive(
    const float* __restrict__ Q, const float* __restrict__ K,
    const float* __restrict__ V, const int* __restrict__ M,
    float* __restrict__ ctx, float* __restrict__ pout)
{
  const int b = blockIdx.x >> 11;
  const int q = blockIdx.x & (LL-1);
  __shared__ float s[LL];
  __shared__ float red[256];
  const int tid = threadIdx.x;
  const float* qp = Q + ((size_t)b*LL + q)*DD;
  for (int kk = tid; kk < LL; kk += 256) {
    const float* kp = K + ((size_t)b*LL + kk)*DD;
    float a = 0.f;
    for (int d = 0; d < DD; ++d) a += qp[d]*kp[d];
    s[kk] = M[((size_t)b*LL + q)*LL + kk] ? a*SCALE : -1e9f;
  }
  __syncthreads();
  float mx = -3e38f;
  for (int kk = tid; kk < LL; kk += 256) mx = fmaxf(mx, s[kk]);
  red[tid] = mx; __syncthreads();
  for (int o = 128; o >= 1; o >>= 1) {
    if (tid < o) red[tid] = fmaxf(red[tid], red[tid+o]);
    __syncthreads();
  }
  const float mrow = red[0]; __syncthreads();
  float sm = 0.f;
  for (int kk = tid; kk < LL; kk += 256) { float e = __expf(s[kk]-mrow); s[kk] = e; sm += e; }
  red[tid] = sm; __syncthreads();
  for (int o = 128; o >= 1; o >>= 1) {
    if (tid < o) red[tid] += red[tid+o];
    __syncthreads();
  }
  const float inv = 1.0f / red[0]; __syncthreads();
  float* prow = pout + ((size_t)b*LL + q)*LL;
  for (int kk = tid; kk < LL; kk += 256) { s[kk] *= inv; prow[kk] = s[kk]; }
  __syncthreads();
  if (tid < DD) {
    float a = 0.f;
    for (int kk = 0; kk < LL; ++kk) a += s[kk]*V[((size_t)b*LL + kk)*DD + tid];
    ctx[((size_t)b*LL + q)*DD + tid] = a;
  }
}

extern "C" void kernel_launch(void* const* d_in, const int* in_sizes, int n_in,
                              void* d_out, int out_size, void* d_ws, size_t ws_size,
                              hipStream_t stream) {
  (void)in_sizes; (void)n_in; (void)out_size;
  const float* Q = (const float*)d_in[0];
  const float* K = (const float*)d_in[1];
  const float* V = (const float*)d_in[2];
  const int*   M = (const int*)d_in[3];
  float* ctx  = (float*)d_out;
  float* pout = ctx + (size_t)BB*LL*DD;
  const size_t IMG = (size_t)BB*NT*16384;        // 8 MB per image
  const size_t NBM = (size_t)BB*LL*(LL/32);      // 2.1M words = 8 MB
  const size_t WS_NEED = IMG*2 + NBM*4;
  if (ws_size >= WS_NEED) {
    unsigned char* kimg = (unsigned char*)d_ws;
    unsigned char* vimg = kimg + IMG;
    unsigned int*  bmw  = (unsigned int*)(vimg + IMG);
    hipFuncSetAttribute(reinterpret_cast<const void*>(attn_main),
                        hipFuncAttributeMaxDynamicSharedMemorySize, LDS_MAIN);
    prep_all<<<12288, 256, 0, stream>>>(K, V, M, kimg, vimg, bmw);
    attn_main<<<256, 512, LDS_MAIN, stream>>>(Q, bmw, kimg, vimg, ctx, pout);
  } else {
    attn_naive<<<BB*LL, 256, 0, stream>>>(Q, K, V, M, ctx, pout);
  }
}